// Round 1
// baseline (1407.946 us; speedup 1.0000x reference)
//
#include <hip/hip_runtime.h>

typedef _Float16 half8 __attribute__((ext_vector_type(8)));
typedef float floatx4 __attribute__((ext_vector_type(4)));

#define NTHR 256

// ---------------- prep: build fp16 fragment-ordered weights + bias sums ----------------
// B-frag layout for mfma_f32_16x16x32_f16 (matches verified A-layout mirror, gemm_bt
// convention): lane L, reg j holds W[n = ntile*16 + (L&15)][k = ktile*32 + (L>>4)*8 + j].
// Buffer layout: [ktile][ntile][lane][8 f16], frag stride 1KB.
__global__ void prep_kernel(const float* __restrict__ wih0, const float* __restrict__ whh0,
                            const float* __restrict__ bih0, const float* __restrict__ bhh0,
                            const float* __restrict__ wih1, const float* __restrict__ whh1,
                            const float* __restrict__ bih1, const float* __restrict__ bhh1,
                            _Float16* __restrict__ w0f, _Float16* __restrict__ w1f,
                            float* __restrict__ bias0, float* __restrict__ bias1)
{
  int stride = gridDim.x * blockDim.x;
  int idx0 = blockIdx.x * blockDim.x + threadIdx.x;
  const int N0 = 6*32*64*8;      // layer0: K=192 (x 64 | h 128), 6 ktiles x 32 ntiles
  const int N1 = 8*32*64*8;      // layer1: K=256 (h1 128 | h 128), 8 ktiles
  for (int e = idx0; e < N0 + N1 + 1024; e += stride) {
    if (e < N0) {
      int j = e & 7; int le = e >> 3; int lane = le & 63; int frag = le >> 6;
      int kt = frag >> 5, ntile = frag & 31;
      int n = ntile*16 + (lane & 15);
      int kk = kt*32 + ((lane >> 4) << 3) + j;
      float v = (kk < 64) ? wih0[n*64 + kk] : whh0[n*128 + (kk - 64)];
      w0f[e] = (_Float16)v;
    } else if (e < N0 + N1) {
      int e2 = e - N0;
      int j = e2 & 7; int le = e2 >> 3; int lane = le & 63; int frag = le >> 6;
      int kt = frag >> 5, ntile = frag & 31;
      int n = ntile*16 + (lane & 15);
      int kk = kt*32 + ((lane >> 4) << 3) + j;
      float v = (kk < 128) ? wih1[n*128 + kk] : whh1[n*128 + (kk - 128)];
      w1f[e2] = (_Float16)v;
    } else {
      int i = e - (N0 + N1);
      if (i < 512) bias0[i] = bih0[i] + bhh0[i];
      else         bias1[i - 512] = bih1[i - 512] + bhh1[i - 512];
    }
  }
}

// ---------------- layer 0: persistent, 2 batch rows per block ----------------
// Weights live in VGPRs as B-frags for all 512 steps. h round-trips through LDS in
// A-frag layout (lane L holds A[m=L&15][k=(L>>4)*8+j]); dead rows m>=2 stay zero.
__global__ __launch_bounds__(256, 1) void lstm_l0(const float* __restrict__ x,
    const _Float16* __restrict__ w0f, const float* __restrict__ bias0,
    _Float16* __restrict__ h1)
{
  const int tid = threadIdx.x;
  const int lane = tid & 63;
  const int w = tid >> 6;            // wave 0..3, owns gates [w*128, w*128+128)
  const int r0 = blockIdx.x * 2;

  __shared__ half8 hA[4*64];         // rec A-frags: 4 ktiles (K=128)
  __shared__ half8 xA[2*64];         // input A-frags: 2 ktiles (K=64)
  __shared__ float gatesBuf[2][512];

  for (int i = tid; i < 4*64*4; i += NTHR) ((int*)hA)[i] = 0;
  for (int i = tid; i < 2*64*4; i += NTHR) ((int*)xA)[i] = 0;

  half8 bf[6][8];                    // 48 frags * 16B = 192 VGPRs/lane, time-invariant
#pragma unroll
  for (int kt = 0; kt < 6; ++kt)
#pragma unroll
    for (int ntl = 0; ntl < 8; ++ntl) {
      int frag = kt*32 + (w*8 + ntl);
      bf[kt][ntl] = *reinterpret_cast<const half8*>(w0f + (size_t)(frag*64 + lane) * 8);
    }

  float bias_v[8];
#pragma unroll
  for (int ntl = 0; ntl < 8; ++ntl)
    bias_v[ntl] = bias0[(w*8 + ntl)*16 + (lane & 15)];

  // epilogue unit: each of the 256 threads owns one (row, hidden-idx) pair
  const int u = (w << 6) + lane;
  const int er = u >> 7, en = u & 127;
  const int erem = en & 31;
  const int eoff = (((en >> 5)*64 + ((erem >> 3) << 4) + er))*8 + (erem & 7);
  float c_st = 0.f;

  __syncthreads();

  for (int t = 0; t < 512; ++t) {
    if (tid < 128) {                 // stage x_t (2 rows x 64) as fp16 A-frags
      int r = tid >> 6, k = tid & 63;
      float xv = x[((size_t)(r0 + r) * 512 + t) * 64 + k];
      int rem = k & 31;
      ((_Float16*)xA)[((k >> 5)*64 + ((rem >> 3) << 4) + r)*8 + (rem & 7)] = (_Float16)xv;
    }
    __syncthreads();                 // xA + hA(prev step) ready

    floatx4 acc[8];
#pragma unroll
    for (int ntl = 0; ntl < 8; ++ntl) { float b = bias_v[ntl]; acc[ntl] = (floatx4){b,b,b,b}; }
#pragma unroll
    for (int kt = 0; kt < 2; ++kt) {
      half8 a = xA[kt*64 + lane];
#pragma unroll
      for (int ntl = 0; ntl < 8; ++ntl)
        acc[ntl] = __builtin_amdgcn_mfma_f32_16x16x32_f16(a, bf[kt][ntl], acc[ntl], 0, 0, 0);
    }
#pragma unroll
    for (int kt = 0; kt < 4; ++kt) {
      half8 a = hA[kt*64 + lane];
#pragma unroll
      for (int ntl = 0; ntl < 8; ++ntl)
        acc[ntl] = __builtin_amdgcn_mfma_f32_16x16x32_f16(a, bf[2+kt][ntl], acc[ntl], 0, 0, 0);
    }

    // C/D layout: col=lane&15, row=(lane>>4)*4+reg -> rows 0,1 live in lanes<16, regs 0,1
    if (lane < 16) {
#pragma unroll
      for (int ntl = 0; ntl < 8; ++ntl) {
        int n = (w*8 + ntl)*16 + lane;
        gatesBuf[0][n] = acc[ntl][0];
        gatesBuf[1][n] = acc[ntl][1];
      }
    }
    __syncthreads();                 // gates ready; also fences xA/hA reads

    {
      float ig = gatesBuf[er][en];
      float fg = gatesBuf[er][en + 128];
      float gg = gatesBuf[er][en + 256];
      float og = gatesBuf[er][en + 384];
      ig = 1.f/(1.f + __expf(-ig));
      fg = 1.f/(1.f + __expf(-fg));
      gg = 1.f - 2.f/(1.f + __expf(2.f*gg));
      og = 1.f/(1.f + __expf(-og));
      c_st = fg*c_st + ig*gg;
      float hv = og * (1.f - 2.f/(1.f + __expf(2.f*c_st)));
      _Float16 hh = (_Float16)hv;
      ((_Float16*)hA)[eoff] = hh;                               // next step's A-frag
      h1[((size_t)(r0 + er) * 512 + t) * 128 + en] = hh;        // inter-layer buffer
    }
    // next iteration's top barrier orders hA writes vs MFMA reads
  }
}

// ---------------- layer 1: same structure, K=256, fused final linear head ----------------
__global__ __launch_bounds__(256, 1) void lstm_l1(const _Float16* __restrict__ h1,
    const _Float16* __restrict__ w1f, const float* __restrict__ bias1,
    const float* __restrict__ wlin, const float* __restrict__ blin,
    float* __restrict__ out)
{
  const int tid = threadIdx.x;
  const int lane = tid & 63;
  const int w = tid >> 6;
  const int r0 = blockIdx.x * 2;

  __shared__ half8 hA[4*64];
  __shared__ half8 iA[4*64];
  __shared__ float gatesBuf[2][512];

  for (int i = tid; i < 4*64*4; i += NTHR) ((int*)hA)[i] = 0;
  for (int i = tid; i < 4*64*4; i += NTHR) ((int*)iA)[i] = 0;

  half8 bf[8][8];                    // 256 VGPRs/lane of weights (1 wave/SIMD, cap 512)
#pragma unroll
  for (int kt = 0; kt < 8; ++kt)
#pragma unroll
    for (int ntl = 0; ntl < 8; ++ntl) {
      int frag = kt*32 + (w*8 + ntl);
      bf[kt][ntl] = *reinterpret_cast<const half8*>(w1f + (size_t)(frag*64 + lane) * 8);
    }
  float bias_v[8];
#pragma unroll
  for (int ntl = 0; ntl < 8; ++ntl)
    bias_v[ntl] = bias1[(w*8 + ntl)*16 + (lane & 15)];

  const int u = (w << 6) + lane;
  const int er = u >> 7, en = u & 127;
  const int erem = en & 31;
  const int eoff = (((en >> 5)*64 + ((erem >> 3) << 4) + er))*8 + (erem & 7);
  const float wl = wlin[en];
  float c_st = 0.f;
  float h_last = 0.f;

  __syncthreads();

  for (int t = 0; t < 512; ++t) {
    {                                // stage h1_t (2 rows x 128 fp16)
      int r = tid >> 7, n = tid & 127;
      _Float16 v = h1[((size_t)(r0 + r) * 512 + t) * 128 + n];
      int rem = n & 31;
      ((_Float16*)iA)[((n >> 5)*64 + ((rem >> 3) << 4) + r)*8 + (rem & 7)] = v;
    }
    __syncthreads();

    floatx4 acc[8];
#pragma unroll
    for (int ntl = 0; ntl < 8; ++ntl) { float b = bias_v[ntl]; acc[ntl] = (floatx4){b,b,b,b}; }
#pragma unroll
    for (int kt = 0; kt < 4; ++kt) {
      half8 a = iA[kt*64 + lane];
#pragma unroll
      for (int ntl = 0; ntl < 8; ++ntl)
        acc[ntl] = __builtin_amdgcn_mfma_f32_16x16x32_f16(a, bf[kt][ntl], acc[ntl], 0, 0, 0);
    }
#pragma unroll
    for (int kt = 0; kt < 4; ++kt) {
      half8 a = hA[kt*64 + lane];
#pragma unroll
      for (int ntl = 0; ntl < 8; ++ntl)
        acc[ntl] = __builtin_amdgcn_mfma_f32_16x16x32_f16(a, bf[4+kt][ntl], acc[ntl], 0, 0, 0);
    }
    if (lane < 16) {
#pragma unroll
      for (int ntl = 0; ntl < 8; ++ntl) {
        int n = (w*8 + ntl)*16 + lane;
        gatesBuf[0][n] = acc[ntl][0];
        gatesBuf[1][n] = acc[ntl][1];
      }
    }
    __syncthreads();
    {
      float ig = gatesBuf[er][en];
      float fg = gatesBuf[er][en + 128];
      float gg = gatesBuf[er][en + 256];
      float og = gatesBuf[er][en + 384];
      ig = 1.f/(1.f + __expf(-ig));
      fg = 1.f/(1.f + __expf(-fg));
      gg = 1.f - 2.f/(1.f + __expf(2.f*gg));
      og = 1.f/(1.f + __expf(-og));
      c_st = fg*c_st + ig*gg;
      h_last = og * (1.f - 2.f/(1.f + __expf(2.f*c_st)));
      ((_Float16*)hA)[eoff] = (_Float16)h_last;
    }
  }

  // final head: out[r] = sum_n h_last[r][n]*wlin[n] + blin
  __syncthreads();
  ((float*)gatesBuf)[u] = h_last * wl;
  __syncthreads();
  if (tid < 2) {
    float s = blin[0];
    for (int n = 0; n < 128; ++n) s += ((float*)gatesBuf)[tid*128 + n];
    out[r0 + tid] = s;
  }
}

extern "C" void kernel_launch(void* const* d_in, const int* in_sizes, int n_in,
                              void* d_out, int out_size, void* d_ws, size_t ws_size,
                              hipStream_t stream)
{
  const float* x    = (const float*)d_in[0];
  const float* wih0 = (const float*)d_in[1];
  const float* whh0 = (const float*)d_in[2];
  const float* bih0 = (const float*)d_in[3];
  const float* bhh0 = (const float*)d_in[4];
  const float* wih1 = (const float*)d_in[5];
  const float* whh1 = (const float*)d_in[6];
  const float* bih1 = (const float*)d_in[7];
  const float* bhh1 = (const float*)d_in[8];
  const float* wlin = (const float*)d_in[9];
  const float* blin = (const float*)d_in[10];
  float* out = (float*)d_out;

  char* ws = (char*)d_ws;
  _Float16* w0f = (_Float16*)(ws);               // 196608 B
  _Float16* w1f = (_Float16*)(ws + 196608);      // 262144 B
  float* bias0  = (float*)(ws + 458752);         // 2048 B
  float* bias1  = (float*)(ws + 460800);         // 2048 B
  _Float16* h1  = (_Float16*)(ws + 1048576);     // 64 MB inter-layer buffer

  prep_kernel<<<256, 256, 0, stream>>>(wih0, whh0, bih0, bhh0, wih1, whh1, bih1, bhh1,
                                       w0f, w1f, bias0, bias1);
  lstm_l0<<<256, 256, 0, stream>>>(x, w0f, bias0, h1);
  lstm_l1<<<256, 256, 0, stream>>>(h1, w1f, bias1, wlin, blin, out);
}

// Round 2
// 1160.891 us; speedup vs baseline: 1.2128x; 1.2128x over previous
//
#include <hip/hip_runtime.h>

typedef _Float16 half8 __attribute__((ext_vector_type(8)));
typedef _Float16 half4 __attribute__((ext_vector_type(4)));
typedef float floatx4 __attribute__((ext_vector_type(4)));

// ---------------- prep: fp16 fragment-ordered weights + bias sums ----------------
// B-frag layout for mfma_f32_16x16x32_f16: lane L, reg j holds
// W[n = ntile*16 + (L&15)][k = ktile*32 + (L>>4)*8 + j].
// Buffer: [ktile][ntile(32)][lane(64)][8 f16]. Verified correct in round 1.
__global__ void prep_kernel(const float* __restrict__ wih0, const float* __restrict__ whh0,
                            const float* __restrict__ bih0, const float* __restrict__ bhh0,
                            const float* __restrict__ wih1, const float* __restrict__ whh1,
                            const float* __restrict__ bih1, const float* __restrict__ bhh1,
                            _Float16* __restrict__ w0f, _Float16* __restrict__ w1f,
                            float* __restrict__ bias0, float* __restrict__ bias1)
{
  int stride = gridDim.x * blockDim.x;
  int idx0 = blockIdx.x * blockDim.x + threadIdx.x;
  const int N0 = 6*32*64*8;      // layer0: K=192 (x 64 | h 128)
  const int N1 = 8*32*64*8;      // layer1: K=256 (h1 128 | h 128)
  for (int e = idx0; e < N0 + N1 + 1024; e += stride) {
    if (e < N0) {
      int j = e & 7; int le = e >> 3; int lane = le & 63; int frag = le >> 6;
      int kt = frag >> 5, ntile = frag & 31;
      int n = ntile*16 + (lane & 15);
      int kk = kt*32 + ((lane >> 4) << 3) + j;
      float v = (kk < 64) ? wih0[n*64 + kk] : whh0[n*128 + (kk - 64)];
      w0f[e] = (_Float16)v;
    } else if (e < N0 + N1) {
      int e2 = e - N0;
      int j = e2 & 7; int le = e2 >> 3; int lane = le & 63; int frag = le >> 6;
      int kt = frag >> 5, ntile = frag & 31;
      int n = ntile*16 + (lane & 15);
      int kk = kt*32 + ((lane >> 4) << 3) + j;
      float v = (kk < 128) ? wih1[n*128 + kk] : whh1[n*128 + (kk - 128)];
      w1f[e2] = (_Float16)v;
    } else {
      int i = e - (N0 + N1);
      if (i < 512) bias0[i] = bih0[i] + bhh0[i];
      else         bias1[i - 512] = bih1[i - 512] + bhh1[i - 512];
    }
  }
}

// A-frag half-offset for element (r, k): ((k>>5)*64 + ((k&31)>>3)*16 + r)*8 + (k&7)

// ---------------- layer 0: 8 waves, wave w owns gate cols [w*16,(w+1)*16) of all 4 gates ----
__global__ __launch_bounds__(512, 2) void lstm_l0(const float* __restrict__ x,
    const _Float16* __restrict__ w0f, const float* __restrict__ bias0,
    _Float16* __restrict__ h1out)
{
  const int tid = threadIdx.x;
  const int lane = tid & 63;
  const int w = tid >> 6;                 // wave 0..7
  const int r0 = blockIdx.x * 2;

  __shared__ half8 xA[2][2*64];           // double-buffered input A-frags (K=64)
  __shared__ half8 hA[2][4*64];           // double-buffered recurrent A-frags (K=128)
  __shared__ _Float16 hist[16][2][128];   // h history ring for coalesced flush

  for (int i = tid; i < 2*2*64*4; i += 512) ((int*)xA)[i] = 0;
  for (int i = tid; i < 2*4*64*4; i += 512) ((int*)hA)[i] = 0;

  // ntile for (gate g, wave w) = g*8 + w  ->  gate col n = g*128 + w*16 + (lane&15)
  half8 bf[6][4];                         // 24 frags = 96 VGPRs, time-invariant
#pragma unroll
  for (int kt = 0; kt < 6; ++kt)
#pragma unroll
    for (int g = 0; g < 4; ++g) {
      int frag = kt*32 + (g*8 + w);
      bf[kt][g] = *reinterpret_cast<const half8*>(w0f + (size_t)(frag*64 + lane)*8);
      asm volatile("" : "+v"(bf[kt][g]));  // pin: defeat remat-into-loop
    }
  float bias_v[4];
#pragma unroll
  for (int g = 0; g < 4; ++g) bias_v[g] = bias0[g*128 + w*16 + (lane & 15)];

  const int sr = tid >> 5;                // staging (tid<64): row
  const int sk = (tid & 31) * 2;          // staging: k pair
  const int en = w*16 + (lane & 15);      // epilogue col (lanes<16)
  const int ebase = ((en>>5)*64 + ((en&31)>>3)*16)*8 + (en&7);
  float c0 = 0.f, c1 = 0.f;

  float2 xpre;
  if (tid < 64) {
    xpre = *reinterpret_cast<const float2*>(x + ((size_t)(r0 + sr)*512 + 0)*64 + sk);
    int off = ((sk>>5)*64 + ((sk&31)>>3)*16 + sr)*8 + (sk&7);
    ((_Float16*)xA[0])[off]   = (_Float16)xpre.x;
    ((_Float16*)xA[0])[off+1] = (_Float16)xpre.y;
  }
  __syncthreads();

  for (int t = 0; t < 512; ++t) {
    // coalesced flush of steps t-8..t-1 (slots disjoint from this step's writes)
    if ((t & 7) == 0 && t != 0) {
      int tbase = t - 8;
      int r = tid >> 8, rest = tid & 255;
      int dt = rest >> 5, n = (rest & 31) * 4;
      half4 v = *reinterpret_cast<const half4*>(&hist[(tbase + dt) & 15][r][n]);
      *reinterpret_cast<half4*>(h1out + ((size_t)(r0 + r)*512 + tbase + dt)*128 + n) = v;
    }
    // prefetch x(t+1) — latency hidden behind MFMA+epilogue
    if (tid < 64) {
      int tt = (t + 1 < 512) ? t + 1 : 511;
      xpre = *reinterpret_cast<const float2*>(x + ((size_t)(r0 + sr)*512 + tt)*64 + sk);
    }

    const int cur = t & 1;
    floatx4 acc[4];
#pragma unroll
    for (int g = 0; g < 4; ++g) { float b = bias_v[g]; acc[g] = (floatx4){b,b,b,b}; }
#pragma unroll
    for (int kt = 0; kt < 2; ++kt) {
      half8 a = xA[cur][kt*64 + lane];
#pragma unroll
      for (int g = 0; g < 4; ++g)
        acc[g] = __builtin_amdgcn_mfma_f32_16x16x32_f16(a, bf[kt][g], acc[g], 0, 0, 0);
    }
#pragma unroll
    for (int kt = 0; kt < 4; ++kt) {
      half8 a = hA[cur][kt*64 + lane];
#pragma unroll
      for (int g = 0; g < 4; ++g)
        acc[g] = __builtin_amdgcn_mfma_f32_16x16x32_f16(a, bf[2+kt][g], acc[g], 0, 0, 0);
    }

    // in-register epilogue: lane<16 holds i,f,g,o for col en, rows 0..1 (C/D: col=lane&15,row=reg)
    if (lane < 16) {
      float i0 = acc[0][0], i1 = acc[0][1];
      float f0 = acc[1][0], f1 = acc[1][1];
      float g0 = acc[2][0], g1 = acc[2][1];
      float o0 = acc[3][0], o1 = acc[3][1];
      i0 = 1.f/(1.f+__expf(-i0)); i1 = 1.f/(1.f+__expf(-i1));
      f0 = 1.f/(1.f+__expf(-f0)); f1 = 1.f/(1.f+__expf(-f1));
      g0 = 1.f - 2.f/(1.f+__expf(2.f*g0)); g1 = 1.f - 2.f/(1.f+__expf(2.f*g1));
      o0 = 1.f/(1.f+__expf(-o0)); o1 = 1.f/(1.f+__expf(-o1));
      c0 = f0*c0 + i0*g0;
      c1 = f1*c1 + i1*g1;
      float h0 = o0*(1.f - 2.f/(1.f+__expf(2.f*c0)));
      float h1v = o1*(1.f - 2.f/(1.f+__expf(2.f*c1)));
      _Float16 hh0 = (_Float16)h0, hh1 = (_Float16)h1v;
      const int nxt = cur ^ 1;
      ((_Float16*)hA[nxt])[ebase]     = hh0;   // r=0
      ((_Float16*)hA[nxt])[ebase + 8] = hh1;   // r=1
      hist[t & 15][0][en] = hh0;
      hist[t & 15][1][en] = hh1;
    }
    if (tid < 64) {
      const int nxt = (t + 1) & 1;
      int off = ((sk>>5)*64 + ((sk&31)>>3)*16 + sr)*8 + (sk&7);
      ((_Float16*)xA[nxt])[off]   = (_Float16)xpre.x;
      ((_Float16*)xA[nxt])[off+1] = (_Float16)xpre.y;
    }
    __syncthreads();                      // single barrier per step
  }
  // final flush: steps 504..511
  {
    int tbase = 504;
    int r = tid >> 8, rest = tid & 255;
    int dt = rest >> 5, n = (rest & 31) * 4;
    half4 v = *reinterpret_cast<const half4*>(&hist[(tbase + dt) & 15][r][n]);
    *reinterpret_cast<half4*>(h1out + ((size_t)(r0 + r)*512 + tbase + dt)*128 + n) = v;
  }
}

// ---------------- layer 1: same structure, K=256, fused linear head ----------------
__global__ __launch_bounds__(512, 2) void lstm_l1(const _Float16* __restrict__ h1in,
    const _Float16* __restrict__ w1f, const float* __restrict__ bias1,
    const float* __restrict__ wlin, const float* __restrict__ blin,
    float* __restrict__ out)
{
  const int tid = threadIdx.x;
  const int lane = tid & 63;
  const int w = tid >> 6;
  const int r0 = blockIdx.x * 2;

  __shared__ half8 iA[2][4*64];
  __shared__ half8 hA[2][4*64];
  __shared__ float head[256];

  for (int i = tid; i < 2*4*64*4; i += 512) ((int*)iA)[i] = 0;
  for (int i = tid; i < 2*4*64*4; i += 512) ((int*)hA)[i] = 0;

  half8 bf[8][4];                         // 32 frags = 128 VGPRs
#pragma unroll
  for (int kt = 0; kt < 8; ++kt)
#pragma unroll
    for (int g = 0; g < 4; ++g) {
      int frag = kt*32 + (g*8 + w);
      bf[kt][g] = *reinterpret_cast<const half8*>(w1f + (size_t)(frag*64 + lane)*8);
      asm volatile("" : "+v"(bf[kt][g]));
    }
  float bias_v[4];
#pragma unroll
  for (int g = 0; g < 4; ++g) bias_v[g] = bias1[g*128 + w*16 + (lane & 15)];

  const int sr = tid >> 6;                // staging (tid<128): row
  const int sn = (tid & 63) * 2;          // staging: n pair (fp16 passthrough)
  const int soff = ((sn>>5)*64 + ((sn&31)>>3)*16 + sr)*8 + (sn&7);
  const int en = w*16 + (lane & 15);
  const int ebase = ((en>>5)*64 + ((en&31)>>3)*16)*8 + (en&7);
  const float wl = (lane < 16) ? wlin[en] : 0.f;
  float c0 = 0.f, c1 = 0.f;
  float hl0 = 0.f, hl1 = 0.f;

  unsigned int hpre;
  if (tid < 128) {
    hpre = *reinterpret_cast<const unsigned int*>(h1in + ((size_t)(r0 + sr)*512 + 0)*128 + sn);
    *reinterpret_cast<unsigned int*>(((_Float16*)iA[0]) + soff) = hpre;
  }
  __syncthreads();

  for (int t = 0; t < 512; ++t) {
    if (tid < 128) {
      int tt = (t + 1 < 512) ? t + 1 : 511;
      hpre = *reinterpret_cast<const unsigned int*>(h1in + ((size_t)(r0 + sr)*512 + tt)*128 + sn);
    }

    const int cur = t & 1;
    floatx4 acc[4];
#pragma unroll
    for (int g = 0; g < 4; ++g) { float b = bias_v[g]; acc[g] = (floatx4){b,b,b,b}; }
#pragma unroll
    for (int kt = 0; kt < 4; ++kt) {
      half8 a = iA[cur][kt*64 + lane];
#pragma unroll
      for (int g = 0; g < 4; ++g)
        acc[g] = __builtin_amdgcn_mfma_f32_16x16x32_f16(a, bf[kt][g], acc[g], 0, 0, 0);
    }
#pragma unroll
    for (int kt = 0; kt < 4; ++kt) {
      half8 a = hA[cur][kt*64 + lane];
#pragma unroll
      for (int g = 0; g < 4; ++g)
        acc[g] = __builtin_amdgcn_mfma_f32_16x16x32_f16(a, bf[4+kt][g], acc[g], 0, 0, 0);
    }

    if (lane < 16) {
      float i0 = acc[0][0], i1 = acc[0][1];
      float f0 = acc[1][0], f1 = acc[1][1];
      float g0 = acc[2][0], g1 = acc[2][1];
      float o0 = acc[3][0], o1 = acc[3][1];
      i0 = 1.f/(1.f+__expf(-i0)); i1 = 1.f/(1.f+__expf(-i1));
      f0 = 1.f/(1.f+__expf(-f0)); f1 = 1.f/(1.f+__expf(-f1));
      g0 = 1.f - 2.f/(1.f+__expf(2.f*g0)); g1 = 1.f - 2.f/(1.f+__expf(2.f*g1));
      o0 = 1.f/(1.f+__expf(-o0)); o1 = 1.f/(1.f+__expf(-o1));
      c0 = f0*c0 + i0*g0;
      c1 = f1*c1 + i1*g1;
      hl0 = o0*(1.f - 2.f/(1.f+__expf(2.f*c0)));
      hl1 = o1*(1.f - 2.f/(1.f+__expf(2.f*c1)));
      const int nxt = cur ^ 1;
      ((_Float16*)hA[nxt])[ebase]     = (_Float16)hl0;
      ((_Float16*)hA[nxt])[ebase + 8] = (_Float16)hl1;
    }
    if (tid < 128) {
      const int nxt = (t + 1) & 1;
      *reinterpret_cast<unsigned int*>(((_Float16*)iA[nxt]) + soff) = hpre;
    }
    __syncthreads();
  }

  // fused head: out[r] = sum_n h_last[r][n]*wlin[n] + blin
  if (lane < 16) {
    head[en]       = hl0 * wl;
    head[128 + en] = hl1 * wl;
  }
  __syncthreads();
  if (tid < 2) {
    float s = blin[0];
    for (int n = 0; n < 128; ++n) s += head[tid*128 + n];
    out[r0 + tid] = s;
  }
}

extern "C" void kernel_launch(void* const* d_in, const int* in_sizes, int n_in,
                              void* d_out, int out_size, void* d_ws, size_t ws_size,
                              hipStream_t stream)
{
  const float* x    = (const float*)d_in[0];
  const float* wih0 = (const float*)d_in[1];
  const float* whh0 = (const float*)d_in[2];
  const float* bih0 = (const float*)d_in[3];
  const float* bhh0 = (const float*)d_in[4];
  const float* wih1 = (const float*)d_in[5];
  const float* whh1 = (const float*)d_in[6];
  const float* bih1 = (const float*)d_in[7];
  const float* bhh1 = (const float*)d_in[8];
  const float* wlin = (const float*)d_in[9];
  const float* blin = (const float*)d_in[10];
  float* out = (float*)d_out;

  char* ws = (char*)d_ws;
  _Float16* w0f = (_Float16*)(ws);               // 196608 B
  _Float16* w1f = (_Float16*)(ws + 196608);      // 262144 B
  float* bias0  = (float*)(ws + 458752);         // 2048 B
  float* bias1  = (float*)(ws + 460800);         // 2048 B
  _Float16* h1  = (_Float16*)(ws + 1048576);     // 64 MB inter-layer buffer

  prep_kernel<<<256, 256, 0, stream>>>(wih0, whh0, bih0, bhh0, wih1, whh1, bih1, bhh1,
                                       w0f, w1f, bias0, bias1);
  lstm_l0<<<256, 512, 0, stream>>>(x, w0f, bias0, h1);
  lstm_l1<<<256, 512, 0, stream>>>(h1, w1f, bias1, wlin, blin, out);
}

// Round 3
// 904.006 us; speedup vs baseline: 1.5575x; 1.2842x over previous
//
#include <hip/hip_runtime.h>

typedef _Float16 half8 __attribute__((ext_vector_type(8)));
typedef _Float16 half4 __attribute__((ext_vector_type(4)));
typedef float floatx4 __attribute__((ext_vector_type(4)));

__device__ __forceinline__ float fast_rcp(float x) { return __builtin_amdgcn_rcpf(x); }
__device__ __forceinline__ float fast_sigmoid(float x) {
  return fast_rcp(1.f + __expf(-x));
}
__device__ __forceinline__ float fast_tanh(float x) {
  return 1.f - 2.f * fast_rcp(1.f + __expf(2.f * x));
}

// ---------------- prep: fp16 fragment-ordered weights + bias sums ----------------
// B-frag layout for mfma_f32_16x16x32_f16: lane L, reg j holds
// W[n = ntile*16 + (L&15)][k = ktile*32 + (L>>4)*8 + j].
// Buffer: [ktile][ntile(32)][lane(64)][8 f16]. Verified correct in rounds 1-2.
__global__ void prep_kernel(const float* __restrict__ wih0, const float* __restrict__ whh0,
                            const float* __restrict__ bih0, const float* __restrict__ bhh0,
                            const float* __restrict__ wih1, const float* __restrict__ whh1,
                            const float* __restrict__ bih1, const float* __restrict__ bhh1,
                            _Float16* __restrict__ w0f, _Float16* __restrict__ w1f,
                            float* __restrict__ bias0, float* __restrict__ bias1)
{
  int stride = gridDim.x * blockDim.x;
  int idx0 = blockIdx.x * blockDim.x + threadIdx.x;
  const int N0 = 6*32*64*8;      // layer0: K=192 (x 64 | h 128)
  const int N1 = 8*32*64*8;      // layer1: K=256 (h1 128 | h 128)
  for (int e = idx0; e < N0 + N1 + 1024; e += stride) {
    if (e < N0) {
      int j = e & 7; int le = e >> 3; int lane = le & 63; int frag = le >> 6;
      int kt = frag >> 5, ntile = frag & 31;
      int n = ntile*16 + (lane & 15);
      int kk = kt*32 + ((lane >> 4) << 3) + j;
      float v = (kk < 64) ? wih0[n*64 + kk] : whh0[n*128 + (kk - 64)];
      w0f[e] = (_Float16)v;
    } else if (e < N0 + N1) {
      int e2 = e - N0;
      int j = e2 & 7; int le = e2 >> 3; int lane = le & 63; int frag = le >> 6;
      int kt = frag >> 5, ntile = frag & 31;
      int n = ntile*16 + (lane & 15);
      int kk = kt*32 + ((lane >> 4) << 3) + j;
      float v = (kk < 128) ? wih1[n*128 + kk] : whh1[n*128 + (kk - 128)];
      w1f[e2] = (_Float16)v;
    } else {
      int i = e - (N0 + N1);
      if (i < 512) bias0[i] = bih0[i] + bhh0[i];
      else         bias1[i - 512] = bih1[i - 512] + bhh1[i - 512];
    }
  }
}

// A-frag half-offset for element (r, k): ((k>>5)*64 + ((k&31)>>3)*16 + r)*8 + (k&7)

// ---------------- layer 0: 8 waves, wave w owns gate cols [w*16,(w+1)*16) of all 4 gates ----
__global__ __launch_bounds__(512, 2) void lstm_l0(const float* __restrict__ x,
    const _Float16* __restrict__ w0f, const float* __restrict__ bias0,
    _Float16* __restrict__ h1out)
{
  const int tid = threadIdx.x;
  const int lane = tid & 63;
  const int w = tid >> 6;                 // wave 0..7
  const int r0 = blockIdx.x * 2;

  __shared__ half8 xA[2][2*64];           // double-buffered input A-frags (K=64)
  __shared__ half8 hA[2][4*64];           // double-buffered recurrent A-frags (K=128)
  __shared__ _Float16 hist[16][2][128];   // h history ring for coalesced flush

  for (int i = tid; i < 2*2*64*4; i += 512) ((int*)xA)[i] = 0;
  for (int i = tid; i < 2*4*64*4; i += 512) ((int*)hA)[i] = 0;

  // ntile for (gate g, wave w) = g*8 + w  ->  gate col n = g*128 + w*16 + (lane&15)
  half8 bf[6][4];                         // 24 frags = 96 regs, pinned to AGPRs
#pragma unroll
  for (int kt = 0; kt < 6; ++kt)
#pragma unroll
    for (int g = 0; g < 4; ++g) {
      int frag = kt*32 + (g*8 + w);
      bf[kt][g] = *reinterpret_cast<const half8*>(w0f + (size_t)(frag*64 + lane)*8);
      asm volatile("" : "+a"(bf[kt][g]));  // pin into AGPRs; MFMA reads B from AGPR directly
    }
  float bias_v[4];
#pragma unroll
  for (int g = 0; g < 4; ++g) bias_v[g] = bias0[g*128 + w*16 + (lane & 15)];

  const int sr = tid >> 5;                // staging (tid<64): row
  const int sk = (tid & 31) * 2;          // staging: k pair
  const int en = w*16 + (lane & 15);      // epilogue col (lanes<16)
  const int ebase = ((en>>5)*64 + ((en&31)>>3)*16)*8 + (en&7);
  float c0 = 0.f, c1 = 0.f;

  float2 xpre;
  if (tid < 64) {
    xpre = *reinterpret_cast<const float2*>(x + ((size_t)(r0 + sr)*512 + 0)*64 + sk);
    int off = ((sk>>5)*64 + ((sk&31)>>3)*16 + sr)*8 + (sk&7);
    ((_Float16*)xA[0])[off]   = (_Float16)xpre.x;
    ((_Float16*)xA[0])[off+1] = (_Float16)xpre.y;
  }
  __syncthreads();

  for (int t = 0; t < 512; ++t) {
    // coalesced flush of steps t-8..t-1 (slots disjoint from this step's writes)
    if ((t & 7) == 0 && t != 0) {
      int tbase = t - 8;
      int r = tid >> 8, rest = tid & 255;
      int dt = rest >> 5, n = (rest & 31) * 4;
      half4 v = *reinterpret_cast<const half4*>(&hist[(tbase + dt) & 15][r][n]);
      *reinterpret_cast<half4*>(h1out + ((size_t)(r0 + r)*512 + tbase + dt)*128 + n) = v;
    }
    // prefetch x(t+1) — latency hidden behind MFMA+epilogue
    if (tid < 64) {
      int tt = (t + 1 < 512) ? t + 1 : 511;
      xpre = *reinterpret_cast<const float2*>(x + ((size_t)(r0 + sr)*512 + tt)*64 + sk);
    }

    const int cur = t & 1;
    floatx4 acc[4];
#pragma unroll
    for (int g = 0; g < 4; ++g) { float b = bias_v[g]; acc[g] = (floatx4){b,b,b,b}; }
#pragma unroll
    for (int kt = 0; kt < 2; ++kt) {
      half8 a = xA[cur][kt*64 + lane];
#pragma unroll
      for (int g = 0; g < 4; ++g)
        acc[g] = __builtin_amdgcn_mfma_f32_16x16x32_f16(a, bf[kt][g], acc[g], 0, 0, 0);
    }
#pragma unroll
    for (int kt = 0; kt < 4; ++kt) {
      half8 a = hA[cur][kt*64 + lane];
#pragma unroll
      for (int g = 0; g < 4; ++g)
        acc[g] = __builtin_amdgcn_mfma_f32_16x16x32_f16(a, bf[2+kt][g], acc[g], 0, 0, 0);
    }

    // in-register epilogue: lane<16 holds i,f,g,o for col en, rows 0..1 (C/D: col=lane&15,row=reg)
    if (lane < 16) {
      float i0 = fast_sigmoid(acc[0][0]), i1 = fast_sigmoid(acc[0][1]);
      float f0 = fast_sigmoid(acc[1][0]), f1 = fast_sigmoid(acc[1][1]);
      float g0 = fast_tanh(acc[2][0]),    g1 = fast_tanh(acc[2][1]);
      float o0 = fast_sigmoid(acc[3][0]), o1 = fast_sigmoid(acc[3][1]);
      c0 = f0*c0 + i0*g0;
      c1 = f1*c1 + i1*g1;
      float h0  = o0*fast_tanh(c0);
      float h1v = o1*fast_tanh(c1);
      _Float16 hh0 = (_Float16)h0, hh1 = (_Float16)h1v;
      const int nxt = cur ^ 1;
      ((_Float16*)hA[nxt])[ebase]     = hh0;   // r=0
      ((_Float16*)hA[nxt])[ebase + 8] = hh1;   // r=1
      hist[t & 15][0][en] = hh0;
      hist[t & 15][1][en] = hh1;
    }
    if (tid < 64) {
      const int nxt = (t + 1) & 1;
      int off = ((sk>>5)*64 + ((sk&31)>>3)*16 + sr)*8 + (sk&7);
      ((_Float16*)xA[nxt])[off]   = (_Float16)xpre.x;
      ((_Float16*)xA[nxt])[off+1] = (_Float16)xpre.y;
    }
    __syncthreads();                      // single barrier per step
  }
  // final flush: steps 504..511
  {
    int tbase = 504;
    int r = tid >> 8, rest = tid & 255;
    int dt = rest >> 5, n = (rest & 31) * 4;
    half4 v = *reinterpret_cast<const half4*>(&hist[(tbase + dt) & 15][r][n]);
    *reinterpret_cast<half4*>(h1out + ((size_t)(r0 + r)*512 + tbase + dt)*128 + n) = v;
  }
}

// ---------------- layer 1: same structure, K=256, fused linear head ----------------
__global__ __launch_bounds__(512, 2) void lstm_l1(const _Float16* __restrict__ h1in,
    const _Float16* __restrict__ w1f, const float* __restrict__ bias1,
    const float* __restrict__ wlin, const float* __restrict__ blin,
    float* __restrict__ out)
{
  const int tid = threadIdx.x;
  const int lane = tid & 63;
  const int w = tid >> 6;
  const int r0 = blockIdx.x * 2;

  __shared__ half8 iA[2][4*64];
  __shared__ half8 hA[2][4*64];
  __shared__ float head[256];

  for (int i = tid; i < 2*4*64*4; i += 512) ((int*)iA)[i] = 0;
  for (int i = tid; i < 2*4*64*4; i += 512) ((int*)hA)[i] = 0;

  half8 bf[8][4];                         // 32 frags = 128 regs, pinned to AGPRs
#pragma unroll
  for (int kt = 0; kt < 8; ++kt)
#pragma unroll
    for (int g = 0; g < 4; ++g) {
      int frag = kt*32 + (g*8 + w);
      bf[kt][g] = *reinterpret_cast<const half8*>(w1f + (size_t)(frag*64 + lane)*8);
      asm volatile("" : "+a"(bf[kt][g]));
    }
  float bias_v[4];
#pragma unroll
  for (int g = 0; g < 4; ++g) bias_v[g] = bias1[g*128 + w*16 + (lane & 15)];

  const int sr = tid >> 6;                // staging (tid<128): row
  const int sn = (tid & 63) * 2;          // staging: n pair (fp16 passthrough)
  const int soff = ((sn>>5)*64 + ((sn&31)>>3)*16 + sr)*8 + (sn&7);
  const int en = w*16 + (lane & 15);
  const int ebase = ((en>>5)*64 + ((en&31)>>3)*16)*8 + (en&7);
  const float wl = (lane < 16) ? wlin[en] : 0.f;
  float c0 = 0.f, c1 = 0.f;
  float hl0 = 0.f, hl1 = 0.f;

  unsigned int hpre;
  if (tid < 128) {
    hpre = *reinterpret_cast<const unsigned int*>(h1in + ((size_t)(r0 + sr)*512 + 0)*128 + sn);
    *reinterpret_cast<unsigned int*>(((_Float16*)iA[0]) + soff) = hpre;
  }
  __syncthreads();

  for (int t = 0; t < 512; ++t) {
    if (tid < 128) {
      int tt = (t + 1 < 512) ? t + 1 : 511;
      hpre = *reinterpret_cast<const unsigned int*>(h1in + ((size_t)(r0 + sr)*512 + tt)*128 + sn);
    }

    const int cur = t & 1;
    floatx4 acc[4];
#pragma unroll
    for (int g = 0; g < 4; ++g) { float b = bias_v[g]; acc[g] = (floatx4){b,b,b,b}; }
#pragma unroll
    for (int kt = 0; kt < 4; ++kt) {
      half8 a = iA[cur][kt*64 + lane];
#pragma unroll
      for (int g = 0; g < 4; ++g)
        acc[g] = __builtin_amdgcn_mfma_f32_16x16x32_f16(a, bf[kt][g], acc[g], 0, 0, 0);
    }
#pragma unroll
    for (int kt = 0; kt < 4; ++kt) {
      half8 a = hA[cur][kt*64 + lane];
#pragma unroll
      for (int g = 0; g < 4; ++g)
        acc[g] = __builtin_amdgcn_mfma_f32_16x16x32_f16(a, bf[4+kt][g], acc[g], 0, 0, 0);
    }

    if (lane < 16) {
      float i0 = fast_sigmoid(acc[0][0]), i1 = fast_sigmoid(acc[0][1]);
      float f0 = fast_sigmoid(acc[1][0]), f1 = fast_sigmoid(acc[1][1]);
      float g0 = fast_tanh(acc[2][0]),    g1 = fast_tanh(acc[2][1]);
      float o0 = fast_sigmoid(acc[3][0]), o1 = fast_sigmoid(acc[3][1]);
      c0 = f0*c0 + i0*g0;
      c1 = f1*c1 + i1*g1;
      hl0 = o0*fast_tanh(c0);
      hl1 = o1*fast_tanh(c1);
      const int nxt = cur ^ 1;
      ((_Float16*)hA[nxt])[ebase]     = (_Float16)hl0;
      ((_Float16*)hA[nxt])[ebase + 8] = (_Float16)hl1;
    }
    if (tid < 128) {
      const int nxt = (t + 1) & 1;
      *reinterpret_cast<unsigned int*>(((_Float16*)iA[nxt]) + soff) = hpre;
    }
    __syncthreads();
  }

  // fused head: out[r] = sum_n h_last[r][n]*wlin[n] + blin
  if (lane < 16) {
    head[en]       = hl0 * wl;
    head[128 + en] = hl1 * wl;
  }
  __syncthreads();
  if (tid < 2) {
    float s = blin[0];
    for (int n = 0; n < 128; ++n) s += head[tid*128 + n];
    out[r0 + tid] = s;
  }
}

extern "C" void kernel_launch(void* const* d_in, const int* in_sizes, int n_in,
                              void* d_out, int out_size, void* d_ws, size_t ws_size,
                              hipStream_t stream)
{
  const float* x    = (const float*)d_in[0];
  const float* wih0 = (const float*)d_in[1];
  const float* whh0 = (const float*)d_in[2];
  const float* bih0 = (const float*)d_in[3];
  const float* bhh0 = (const float*)d_in[4];
  const float* wih1 = (const float*)d_in[5];
  const float* whh1 = (const float*)d_in[6];
  const float* bih1 = (const float*)d_in[7];
  const float* bhh1 = (const float*)d_in[8];
  const float* wlin = (const float*)d_in[9];
  const float* blin = (const float*)d_in[10];
  float* out = (float*)d_out;

  char* ws = (char*)d_ws;
  _Float16* w0f = (_Float16*)(ws);               // 196608 B
  _Float16* w1f = (_Float16*)(ws + 196608);      // 262144 B
  float* bias0  = (float*)(ws + 458752);         // 2048 B
  float* bias1  = (float*)(ws + 460800);         // 2048 B
  _Float16* h1  = (_Float16*)(ws + 1048576);     // 64 MB inter-layer buffer

  prep_kernel<<<256, 256, 0, stream>>>(wih0, whh0, bih0, bhh0, wih1, whh1, bih1, bhh1,
                                       w0f, w1f, bias0, bias1);
  lstm_l0<<<256, 512, 0, stream>>>(x, w0f, bias0, h1);
  lstm_l1<<<256, 512, 0, stream>>>(h1, w1f, bias1, wlin, blin, out);
}